// Round 5
// baseline (632.984 us; speedup 1.0000x reference)
//
#include <hip/hip_runtime.h>
#include <math.h>

typedef __attribute__((ext_vector_type(8))) short short8;   // 8 bf16 = 4 VGPR
typedef __attribute__((ext_vector_type(4))) float f32x4;

__device__ inline unsigned short f2bf(float f) {
    unsigned int u = __float_as_uint(f);
    u += 0x7fffu + ((u >> 16) & 1u);          // RNE
    return (unsigned short)(u >> 16);
}
__device__ inline float bf2f(unsigned int h) { return __uint_as_float(h << 16); }

#define GLOAD_LDS16(gp, lp)                                                              \
    __builtin_amdgcn_global_load_lds(                                                    \
        (const __attribute__((address_space(1))) unsigned int*)(const void*)(gp),        \
        (__attribute__((address_space(3))) unsigned int*)(void*)(lp), 16, 0, 0)

// ---------------- degree / CSR ----------------

__global__ void init_k(float* deg, int* cnt, int N) {
    int i = blockIdx.x * blockDim.x + threadIdx.x;
    if (i < N) { deg[i] = 1.0f; cnt[i] = 0; }
}

__global__ void deg_cnt_k(const int* __restrict__ dst, const float* __restrict__ w,
                          float* deg, int* cnt, int E) {
    int e = blockIdx.x * blockDim.x + threadIdx.x;
    if (e < E) { int d = dst[e]; atomicAdd(&deg[d], w[e]); atomicAdd(&cnt[d], 1); }
}

__global__ void dinv_k(float* deg, int N) {
    int i = blockIdx.x * blockDim.x + threadIdx.x;
    if (i < N) { float d = deg[i]; deg[i] = d > 0.f ? rsqrtf(d) : 0.f; }
}

__global__ void scan_k(const int* __restrict__ cnt, int* __restrict__ rp,
                       int* __restrict__ ofs, int N) {
    __shared__ int buf[2][1024];
    __shared__ int carry_s;
    int tid = threadIdx.x;
    if (tid == 0) { carry_s = 0; rp[0] = 0; }
    __syncthreads();
    for (int base = 0; base < N; base += 1024) {
        int i = base + tid;
        int v = (i < N) ? cnt[i] : 0;
        int pp = 0;
        buf[0][tid] = v;
        __syncthreads();
        for (int o = 1; o < 1024; o <<= 1) {
            int nv = buf[pp][tid];
            if (tid >= o) nv += buf[pp][tid - o];
            buf[pp ^ 1][tid] = nv;
            pp ^= 1;
            __syncthreads();
        }
        int inc = buf[pp][tid];
        int c = carry_s;
        if (i < N) { rp[i + 1] = c + inc; ofs[i] = c + inc - v; }
        __syncthreads();
        if (tid == 1023) carry_s = c + inc;
        __syncthreads();
    }
}

__global__ void fill_csr_k(const int* __restrict__ src, const int* __restrict__ dst,
                           const float* __restrict__ w, const float* __restrict__ dinv,
                           int* ofs, int* __restrict__ csr_src, float* __restrict__ csr_norm, int E) {
    int e = blockIdx.x * blockDim.x + threadIdx.x;
    if (e < E) {
        int s = src[e], d = dst[e];
        int p = atomicAdd(&ofs[d], 1);
        csr_src[p] = s;
        csr_norm[p] = dinv[s] * w[e] * dinv[d];
    }
}

// ---------------- conversions ----------------

__global__ void cvt_x_k(const float* __restrict__ x, unsigned short* __restrict__ zx, int N) {
    int t = blockIdx.x * blockDim.x + threadIdx.x;
    if (t >= N * 32) return;
    int r = t >> 5, c4 = (t & 31) * 4;
    float4 v = *(const float4*)&x[(size_t)r * 128 + c4];
    uint2 o;
    o.x = (unsigned)f2bf(v.x) | ((unsigned)f2bf(v.y) << 16);
    o.y = (unsigned)f2bf(v.z) | ((unsigned)f2bf(v.w) << 16);
    *(uint2*)&zx[(size_t)r * 256 + 128 + c4] = o;
}

__global__ void cvt_ph_k(const float* __restrict__ ph, unsigned short* __restrict__ d, int N) {
    int t = blockIdx.x * blockDim.x + threadIdx.x;
    if (t >= N * 64) return;
    int r = t >> 6, c4 = (t & 63) * 4;
    float4 v = *(const float4*)&ph[(size_t)r * 256 + c4];
    uint2 o;
    o.x = (unsigned)f2bf(v.x) | ((unsigned)f2bf(v.y) << 16);
    o.y = (unsigned)f2bf(v.z) | ((unsigned)f2bf(v.w) << 16);
    *(uint2*)&d[(size_t)r * 256 + c4] = o;
}

// all weights -> bf16, transposed to Bt[n][k]
__global__ void cvtw_k(const float* W1, const float* W2,
                       const float* Wxz, const float* Whz, const float* Wxr, const float* Whr,
                       const float* Wxh, const float* Whh,
                       unsigned short* Bt1, unsigned short* Bt2,
                       unsigned short* BtZR, unsigned short* BtH) {
    int t = blockIdx.x * blockDim.x + threadIdx.x;
    if (t < 32768) { int k = t >> 8, n = t & 255; Bt1[(size_t)n * 128 + k] = f2bf(W1[t]); return; }
    t -= 32768;
    if (t < 32768) { int k = t >> 7, n = t & 127; Bt2[(size_t)n * 256 + k] = f2bf(W2[t]); return; }
    t -= 32768;
    if (t < 65536) { int k = t >> 8, n = t & 255; BtZR[(size_t)n * 512 + k] = f2bf(Wxz[t]); return; }
    t -= 65536;
    if (t < 65536) { int k = t >> 8, n = t & 255; BtZR[(size_t)n * 512 + 256 + k] = f2bf(Whz[t]); return; }
    t -= 65536;
    if (t < 65536) { int k = t >> 8, n = t & 255; BtZR[(size_t)(256 + n) * 512 + k] = f2bf(Wxr[t]); return; }
    t -= 65536;
    if (t < 65536) { int k = t >> 8, n = t & 255; BtZR[(size_t)(256 + n) * 512 + 256 + k] = f2bf(Whr[t]); return; }
    t -= 65536;
    if (t < 65536) { int k = t >> 8, n = t & 255; BtH[(size_t)n * 512 + k] = f2bf(Wxh[t]); return; }
    t -= 65536;
    if (t < 65536) { int k = t >> 8, n = t & 255; BtH[(size_t)n * 512 + 256 + k] = f2bf(Whh[t]); }
}

__global__ void bias_fuse_k(const float* bxz, const float* bhz, const float* bxr, const float* bhr,
                            const float* bxh, const float* bhh, float* bZR, float* bH) {
    int t = blockIdx.x * blockDim.x + threadIdx.x;
    if (t < 256)       bZR[t] = bxz[t] + bhz[t];
    else if (t < 512)  bZR[t] = bxr[t - 256] + bhr[t - 256];
    else if (t < 768)  bH[t - 512] = bxh[t - 512] + bhh[t - 512];
}

// ---------------- CSR gather (bf16 in, f32 accum, bf16 out) ----------------
template <int EPI>
__global__ void agg_bf_k(const int* __restrict__ rp, const int* __restrict__ cs,
                         const float* __restrict__ cn,
                         const unsigned short* __restrict__ X, int ldx2, int xo2,
                         const float* __restrict__ dinv, const float* __restrict__ bias,
                         unsigned short* __restrict__ Y, int ldy2, int yo2, int N) {
    int wid = (blockIdx.x * blockDim.x + threadIdx.x) >> 6;
    int lane = threadIdx.x & 63;
    if (wid >= N) return;
    const unsigned int* Xu = (const unsigned int*)X;
    float dv = dinv[wid]; dv *= dv;
    unsigned int sv = Xu[(size_t)wid * ldx2 + xo2 + lane];
    float ax = bf2f(sv & 0xffffu) * dv, ay = bf2f(sv >> 16) * dv;
    int p = rp[wid], pe = rp[wid + 1];
    for (; p + 4 <= pe; p += 4) {
        int s0 = cs[p], s1 = cs[p+1], s2 = cs[p+2], s3 = cs[p+3];
        float n0 = cn[p], n1 = cn[p+1], n2 = cn[p+2], n3 = cn[p+3];
        unsigned int v0 = Xu[(size_t)s0 * ldx2 + xo2 + lane];
        unsigned int v1 = Xu[(size_t)s1 * ldx2 + xo2 + lane];
        unsigned int v2 = Xu[(size_t)s2 * ldx2 + xo2 + lane];
        unsigned int v3 = Xu[(size_t)s3 * ldx2 + xo2 + lane];
        ax = fmaf(bf2f(v0 & 0xffffu), n0, ax); ay = fmaf(bf2f(v0 >> 16), n0, ay);
        ax = fmaf(bf2f(v1 & 0xffffu), n1, ax); ay = fmaf(bf2f(v1 >> 16), n1, ay);
        ax = fmaf(bf2f(v2 & 0xffffu), n2, ax); ay = fmaf(bf2f(v2 >> 16), n2, ay);
        ax = fmaf(bf2f(v3 & 0xffffu), n3, ax); ay = fmaf(bf2f(v3 >> 16), n3, ay);
    }
    for (; p < pe; ++p) {
        int s = cs[p]; float nv = cn[p];
        unsigned int v = Xu[(size_t)s * ldx2 + xo2 + lane];
        ax = fmaf(bf2f(v & 0xffffu), nv, ax); ay = fmaf(bf2f(v >> 16), nv, ay);
    }
    if (EPI == 1) {
        ax = fmaxf(ax + bias[lane * 2], 0.f);
        ay = fmaxf(ay + bias[lane * 2 + 1], 0.f);
    }
    unsigned int o = (unsigned)f2bf(ax) | ((unsigned)f2bf(ay) << 16);
    ((unsigned int*)Y)[(size_t)wid * ldy2 + yo2 + lane] = o;
}

// ---------------- head ----------------

__global__ void colsum_bf_k(const unsigned short* __restrict__ Z, float* zsum, int N) {
    int c = threadIdx.x;
    int rpb = (N + gridDim.x - 1) / gridDim.x;
    int r0 = blockIdx.x * rpb, r1 = min(N, r0 + rpb);
    float s = 0.f;
    for (int r = r0; r < r1; ++r) s += bf2f((unsigned int)Z[(size_t)r * 256 + c]);
    atomicAdd(&zsum[c], s);
}

__global__ void head_k(const float* __restrict__ zsum, const float* __restrict__ Wh,
                       const float* __restrict__ bh, float* __restrict__ out, float invN) {
    __shared__ float red[128];
    int c = threadIdx.x;
    red[c] = zsum[c] * invN * Wh[c];
    __syncthreads();
    for (int s = 64; s > 0; s >>= 1) {
        if (c < s) red[c] += red[c + s];
        __syncthreads();
    }
    if (c == 0) out[0] = red[0] + bh[0];
}

// ---------------- bf16 MFMA GEMM, 128x128 tile ----------------
// 2-phase pipeline: double-buffered LDS, counted vmcnt(4), prefetch across barrier.
// LDS linear [row][4 slots of 16B]; bank-conflict-free via pre-swizzled global src:
//   staging lane (r=lane>>2, c=lane&3) fetches global k-slot (c ^ ((r>>1)&3));
//   reader of row rt, k-group g reads slot (g ^ ((rt>>1)&3)).

enum { EPI_G = 0, EPI_P = 1, EPI_ZR = 2, EPI_H = 3 };

__global__ __launch_bounds__(256)
void mm_bf16_k(const unsigned short* __restrict__ A0, const unsigned short* __restrict__ A1,
               int lda0, int lda1, int kb,
               const unsigned short* __restrict__ Bt, int K, int M, int ncb,
               const float* __restrict__ bias,
               const unsigned short* __restrict__ xb1, const unsigned short* __restrict__ xb2,
               void* __restrict__ out, void* __restrict__ out2, int epi)
{
    __shared__ unsigned short Als[2][4096];   // [buf][128 rows x 32 k]
    __shared__ unsigned short Bls[2][4096];

    // XCD-bijective swizzle (m204), bcol fast -> A-panel reuse within an XCD's L2
    int nwg = gridDim.x;
    int bid = blockIdx.x;
    int q = nwg >> 3, r = nwg & 7;
    int xcd = bid & 7;
    int wg = (xcd < r ? xcd * (q + 1) : r * (q + 1) + (xcd - r) * q) + (bid >> 3);
    int brow = wg / ncb, bcol = wg - brow * ncb;
    int row0 = brow * 128, col0 = bcol * 128;

    int t = threadIdx.x;
    int w = t >> 6, lane = t & 63;
    int wr = w >> 1, wc = w & 1;
    int m15 = lane & 15, g = lane >> 4;

    int srow = lane >> 2;                              // row within 16-row chunk
    int skk  = (((lane & 3) ^ ((lane >> 3) & 3)) << 3); // swizzled global k element offset

    f32x4 acc[4][4];
    #pragma unroll
    for (int i = 0; i < 4; ++i)
        #pragma unroll
        for (int j = 0; j < 4; ++j)
            #pragma unroll
            for (int qq = 0; qq < 4; ++qq) acc[i][j][qq] = 0.f;

    auto stage = [&](int buf, int kt) {
        const unsigned short* Ap = A0; int lda = lda0; int ka = kt;
        if (kt >= kb) { Ap = A1; lda = lda1; ka = kt - kb; }
        #pragma unroll
        for (int i = 0; i < 2; ++i) {
            int chunk = i * 4 + w;               // 0..7, per-wave uniform
            int arow = chunk * 16 + srow;
            int gr = row0 + arow; gr = gr < M ? gr : M - 1;
            GLOAD_LDS16(&Ap[(size_t)gr * lda + ka + skk], &Als[buf][chunk * 512]);
            GLOAD_LDS16(&Bt[(size_t)(col0 + arow) * K + kt + skk], &Bls[buf][chunk * 512]);
        }
    };

    int NT = K >> 5;
    stage(0, 0);
    int pb = 0;

    for (int ti = 0; ti < NT; ++ti) {
        if (ti + 1 < NT) {
            stage(pb ^ 1, (ti + 1) << 5);                       // prefetch next tile
            asm volatile("s_waitcnt vmcnt(4)" ::: "memory");    // own 4 loads of tile ti done
        } else {
            asm volatile("s_waitcnt vmcnt(0)" ::: "memory");
        }
        __builtin_amdgcn_s_barrier();                           // tile ti fully in LDS
        __builtin_amdgcn_sched_barrier(0);

        short8 af[4], bfr[4];
        #pragma unroll
        for (int ms = 0; ms < 4; ++ms) {
            int rt = wr * 64 + ms * 16 + m15;
            af[ms] = *(const short8*)&Als[pb][rt * 32 + ((g ^ ((rt >> 1) & 3)) << 3)];
        }
        #pragma unroll
        for (int ns = 0; ns < 4; ++ns) {
            int nt = wc * 64 + ns * 16 + m15;
            bfr[ns] = *(const short8*)&Bls[pb][nt * 32 + ((g ^ ((nt >> 1) & 3)) << 3)];
        }
        asm volatile("s_waitcnt lgkmcnt(0)" ::: "memory");
        __builtin_amdgcn_sched_barrier(0);
        __builtin_amdgcn_s_barrier();                           // reads done -> buffer reusable

        #pragma unroll
        for (int ms = 0; ms < 4; ++ms)
            #pragma unroll
            for (int ns = 0; ns < 4; ++ns)
                acc[ms][ns] = __builtin_amdgcn_mfma_f32_16x16x32_bf16(af[ms], bfr[ns], acc[ms][ns], 0, 0, 0);
        pb ^= 1;
    }

    // epilogue: row = row0 + wr*64 + ms*16 + (lane>>4)*4 + i; col = col0 + wc*64 + ns*16 + m15
    int r4 = (lane >> 4) * 4;
    #pragma unroll
    for (int ms = 0; ms < 4; ++ms) {
        #pragma unroll
        for (int ns = 0; ns < 4; ++ns) {
            int col = col0 + wc * 64 + ns * 16 + m15;
            #pragma unroll
            for (int i = 0; i < 4; ++i) {
                int row = row0 + wr * 64 + ms * 16 + r4 + i;
                if (row >= M) continue;
                float v = acc[ms][ns][i];
                if (epi == EPI_G) {
                    float val = fmaxf(v + bias[col], 0.f) + bf2f((unsigned)xb1[(size_t)row * 256 + col]);
                    ((unsigned short*)out)[(size_t)row * 256 + col] = f2bf(val);
                } else if (epi == EPI_P) {
                    ((unsigned short*)out)[(size_t)row * 128 + col] = f2bf(v);
                } else if (epi == EPI_ZR) {
                    float s = 1.f / (1.f + __expf(-(v + bias[col])));
                    if (col < 256) {
                        ((unsigned short*)out)[(size_t)row * 256 + col] = f2bf(s);   // Z bf16
                    } else {
                        int c2 = col - 256;
                        ((unsigned short*)out2)[(size_t)row * 256 + c2] =
                            f2bf(bf2f((unsigned)xb1[(size_t)row * 256 + c2]) * s);   // q = ph*R
                    }
                } else {  // EPI_H
                    float s = v + bias[col];
                    float e = __expf(2.f * s);
                    float ht = 1.f - 2.f / (e + 1.f);
                    float Zt = bf2f((unsigned)xb2[(size_t)row * 256 + col]);
                    float ph = bf2f((unsigned)xb1[(size_t)row * 256 + col]);
                    ((float*)out)[(size_t)row * 256 + col] = Zt * ph + (1.f - Zt) * ht;
                }
            }
        }
    }
}

// ---------------- launch ----------------

extern "C" void kernel_launch(void* const* d_in, const int* in_sizes, int n_in,
                              void* d_out, int out_size, void* d_ws, size_t ws_size,
                              hipStream_t stream) {
    const float* x      = (const float*)d_in[0];
    const int*   ei     = (const int*)d_in[1];
    const float* ew     = (const float*)d_in[2];
    const float* prev_h = (const float*)d_in[3];
    const float* W1  = (const float*)d_in[4];  const float* b1  = (const float*)d_in[5];
    const float* W2  = (const float*)d_in[6];  const float* b2  = (const float*)d_in[7];
    const float* Wxz = (const float*)d_in[8];  const float* bxz = (const float*)d_in[9];
    const float* Whz = (const float*)d_in[10]; const float* bhz = (const float*)d_in[11];
    const float* Wxr = (const float*)d_in[12]; const float* bxr = (const float*)d_in[13];
    const float* Whr = (const float*)d_in[14]; const float* bhr = (const float*)d_in[15];
    const float* Wxh = (const float*)d_in[16]; const float* bxh = (const float*)d_in[17];
    const float* Whh = (const float*)d_in[18]; const float* bhh = (const float*)d_in[19];
    const float* Whead = (const float*)d_in[20]; const float* bhead = (const float*)d_in[21];

    const int N = in_sizes[0] / 128;
    const int E = in_sizes[2];
    const int* esrc = ei;
    const int* edst = ei + E;

    float* ws = (float*)d_ws;
    size_t o = 0;
    float* dinv     = ws + o; o += (size_t)N;
    int*   cnt      = (int*)(ws + o); o += (size_t)N;
    int*   rowp     = (int*)(ws + o); o += (size_t)N + 4;
    int*   csr_src  = (int*)(ws + o); o += (size_t)E;
    float* csr_norm = ws + o; o += (size_t)E;
    unsigned short* zx   = (unsigned short*)(ws + o); o += (size_t)N * 128;  // [N,256]: z | x
    unsigned short* phb  = (unsigned short*)(ws + o); o += (size_t)N * 128;  // prev_h bf16
    unsigned short* buf1 = (unsigned short*)(ws + o); o += (size_t)N * 128;  // t -> gw2 -> q
    unsigned short* Zbf  = (unsigned short*)(ws + o); o += (size_t)N * 128;  // g_bf -> Z bf16
    unsigned short* Bt1  = (unsigned short*)(ws + o); o += 16384;
    unsigned short* Bt2  = (unsigned short*)(ws + o); o += 16384;
    unsigned short* BtZR = (unsigned short*)(ws + o); o += 131072;
    unsigned short* BtH  = (unsigned short*)(ws + o); o += 65536;
    float* bZR      = ws + o; o += 512;
    float* bH       = ws + o; o += 256;
    float* zsum     = ws + o; o += 128;

    unsigned short* g_bf = Zbf;                     // [N,256] bf16, dead before Z written
    float* hout = (float*)d_out + 1;                // output 1: h [N,256]

    const int TPB = 256;
    int gN = (N + TPB - 1) / TPB;
    int gE = (E + TPB - 1) / TPB;
    int gAgg = (N * 64 + TPB - 1) / TPB;
    int nb = (N + 127) / 128;

    // norm + CSR
    init_k<<<gN, TPB, 0, stream>>>(dinv, cnt, N);
    deg_cnt_k<<<gE, TPB, 0, stream>>>(edst, ew, dinv, cnt, E);
    dinv_k<<<gN, TPB, 0, stream>>>(dinv, N);
    scan_k<<<1, 1024, 0, stream>>>(cnt, rowp, cnt, N);
    fill_csr_k<<<gE, TPB, 0, stream>>>(esrc, edst, ew, dinv, cnt, csr_src, csr_norm, E);

    // conversions
    cvt_x_k<<<(N * 32 + TPB - 1) / TPB, TPB, 0, stream>>>(x, zx, N);
    cvt_ph_k<<<(N * 64 + TPB - 1) / TPB, TPB, 0, stream>>>(prev_h, phb, N);
    cvtw_k<<<1792, TPB, 0, stream>>>(W1, W2, Wxz, Whz, Wxr, Whr, Wxh, Whh, Bt1, Bt2, BtZR, BtH);
    bias_fuse_k<<<3, TPB, 0, stream>>>(bxz, bhz, bxr, bhr, bxh, bhh, bZR, bH);

    // t = agg(x)
    agg_bf_k<0><<<gAgg, TPB, 0, stream>>>(rowp, csr_src, csr_norm, zx, 128, 64, dinv,
                                          nullptr, buf1, 64, 0, N);

    // g = relu(t@W1 + b1) + prev_h  -> g_bf [N,256]
    mm_bf16_k<<<nb * 2, 256, 0, stream>>>(buf1, buf1, 128, 128, 128, Bt1, 128, N, 2,
                                          b1, phb, nullptr, g_bf, nullptr, EPI_G);
    // gw2 = g@W2 -> buf1 [N,128]
    mm_bf16_k<<<nb, 256, 0, stream>>>(g_bf, g_bf, 256, 256, 256, Bt2, 256, N, 1,
                                      nullptr, nullptr, nullptr, buf1, nullptr, EPI_P);
    // z = relu(agg(gw2) + b2) -> zx cols 0..127
    agg_bf_k<1><<<gAgg, TPB, 0, stream>>>(rowp, csr_src, csr_norm, buf1, 64, 0, dinv,
                                          b2, zx, 128, 0, N);

    // head
    hipMemsetAsync(zsum, 0, 128 * sizeof(float), stream);
    colsum_bf_k<<<512, 128, 0, stream>>>(zx, zsum, N);
    head_k<<<1, 128, 0, stream>>>(zsum, Whead, bhead, (float*)d_out, 1.0f / (float)N);

    // Z|R fused GEMM: A = [zx | phb], K=512, Ncols=512 -> Z (bf16) + q
    mm_bf16_k<<<nb * 4, 256, 0, stream>>>(zx, phb, 256, 256, 256, BtZR, 512, N, 4,
                                          bZR, phb, nullptr, Zbf, buf1, EPI_ZR);
    // h GEMM: A = [zx | q], K=512, Ncols=256 -> h (f32, d_out+1)
    mm_bf16_k<<<nb * 2, 256, 0, stream>>>(zx, buf1, 256, 256, 256, BtH, 512, N, 2,
                                          bH, phb, Zbf, hout, nullptr, EPI_H);
}